// Round 16
// baseline (222.025 us; speedup 1.0000x reference)
//
#include <hip/hip_runtime.h>
#include <math.h>

#define NVARS 11
#define NUMT  100
#define NOBS  10
#define MAXIT 50

// workspace layout (floats) — identical to r1..r15
#define E_OFF    0      // inv_init[:11,11:17]  11x6
#define F_OFF    66     // inv_opt[:11,:11]     11x11
#define G4_OFF   187    // inv_opt[:11,11:15]   11x4
#define GP_OFF   231    // P^T P                11x11
#define GPD_OFF  352    // Pd^T Pd
#define GPDD_OFF 473    // Pdd^T Pdd
#define WS_FLOATS 594

#define BSTRIDE 308     // row stride (16B aligned)

typedef float f32x2 __attribute__((ext_vector_type(2)));

__device__ void gj_inv(double (*aug)[34], int N, double* fac, int* piv, int tid, int nthr)
{
    for (int k = 0; k < N; ++k) {
        if (tid == 0) {
            int p = k; double best = fabs(aug[k][k]);
            for (int r = k + 1; r < N; ++r) { double v = fabs(aug[r][k]); if (v > best) { best = v; p = r; } }
            *piv = p;
        }
        __syncthreads();
        int p = *piv;
        if (p != k) {
            for (int c = tid; c < 2 * N; c += nthr) { double t = aug[k][c]; aug[k][c] = aug[p][c]; aug[p][c] = t; }
        }
        __syncthreads();
        double pv = aug[k][k];
        __syncthreads();
        // fused: normalize row k (tid<2N) || fac capture (tid-2N in [0,N)); fac[k] unused
        for (int c = tid; c < 2 * N; c += nthr) aug[k][c] /= pv;
        if (tid >= 2 * N && tid < 2 * N + N) fac[tid - 2 * N] = aug[tid - 2 * N][k];
        __syncthreads();
        for (int idx = tid; idx < N * 2 * N; idx += nthr) {
            int r = idx / (2 * N), c = idx % (2 * N);
            if (r != k) aug[r][c] -= fac[r] * aug[k][c];
        }
        __syncthreads();
    }
}

__global__ __launch_bounds__(128) void setup_kernel(const float* __restrict__ P,
                                                    const float* __restrict__ Pd,
                                                    const float* __restrict__ Pdd,
                                                    float* __restrict__ ws)
{
    __shared__ double G[3][NVARS][NVARS];
    __shared__ double aug[17][34];
    __shared__ double fac[17];
    __shared__ int piv;
    const int tid = threadIdx.x, nthr = 128;

    for (int idx = tid; idx < 3 * 121; idx += nthr) {
        int q = idx / 121, rem = idx % 121, r = rem / 11, c = rem % 11;
        const float* B = (q == 0) ? P : (q == 1) ? Pd : Pdd;
        double s = 0.0;
        for (int t = 0; t < NUMT; ++t) s += (double)B[t * 11 + r] * (double)B[t * 11 + c];
        G[q][r][c] = s;
    }
    __syncthreads();
    for (int idx = tid; idx < 3 * 121; idx += nthr) ws[GP_OFF + idx] = (float)((&G[0][0][0])[idx]);

    for (int idx = tid; idx < 17 * 34; idx += nthr) aug[idx / 34][idx % 34] = 0.0;
    __syncthreads();
    for (int idx = tid; idx < 121; idx += nthr) aug[idx / 11][idx % 11] = G[2][idx / 11][idx % 11];
    if (tid < 66) {
        int r = tid / 11, j = tid % 11;
        const float* src = (r == 0) ? P : (r == 1) ? Pd : (r == 2) ? (P + 99 * 11) : (r == 3) ? (Pd + 99 * 11)
                           : (r == 4) ? (P + 49 * 11) : (P + 74 * 11);
        double v = (double)src[j];
        aug[j][11 + r] = v;
        aug[11 + r][j] = v;
    }
    if (tid < 17) aug[tid][17 + tid] = 1.0;
    __syncthreads();
    gj_inv(aug, 17, fac, &piv, tid, nthr);
    if (tid < 66) { int j = tid / 6, k = tid % 6; ws[E_OFF + tid] = (float)aug[j][17 + 11 + k]; }
    __syncthreads();

    for (int idx = tid; idx < 17 * 34; idx += nthr) aug[idx / 34][idx % 34] = 0.0;
    __syncthreads();
    for (int idx = tid; idx < 121; idx += nthr) {
        int r = idx / 11, c = idx % 11;
        aug[r][c] = 11.0 * G[0][r][c] + G[1][r][c] + G[2][r][c] + ((r == c) ? 1.0 : 0.0);
    }
    if (tid < 44) {
        int r = tid / 11, j = tid % 11;
        const float* src = (r == 0) ? P : (r == 1) ? Pd : (r == 2) ? (P + 99 * 11) : (Pd + 99 * 11);
        double v = (double)src[j];
        aug[j][11 + r] = v;
        aug[11 + r][j] = v;
    }
    if (tid < 15) aug[tid][15 + tid] = 1.0;
    __syncthreads();
    gj_inv(aug, 15, fac, &piv, tid, nthr);
    if (tid < 121) { int j = tid / 11, k = tid % 11; ws[F_OFF + tid] = (float)aug[j][15 + k]; }
    if (tid < 44)  { int j = tid / 4,  k = tid % 4;  ws[G4_OFF + tid] = (float)aug[j][15 + 11 + k]; }
}

__device__ __forceinline__ float sbcast(float v) {
    return __int_as_float(__builtin_amdgcn_readfirstlane(__float_as_int(v)));
}

// solve: 1 element per 128-thread block (2 waves), grid 2048 = 8 blocks/CU (all resident).
// r12/r14/r15 layout. This round: packed-f32x2 phase B (even/odd chains) + Sob hoist.
__global__ __launch_bounds__(128, 4) void solve_kernel(
    const float* __restrict__ P, const float* __restrict__ Pd, const float* __restrict__ Pdd,
    const float* __restrict__ ise, const float* __restrict__ term, const float* __restrict__ via,
    const float* __restrict__ obs, const float* __restrict__ tgt, const float* __restrict__ dtb,
    const float* __restrict__ ws, float* __restrict__ out)
{
    __shared__ __align__(16) float sBc[NVARS][BSTRIDE];   // [j][q*100+t]
    __shared__ __align__(16) float wbc[2][BSTRIDE];       // [axis][q*100+t]
    __shared__ float cst[WS_FLOATS];
    __shared__ float sd456[3][24];    // Gram matvec results (w1 lanes 100..121)
    __shared__ float Dred[6][12];
    __shared__ float mlin[2][12];
    __shared__ __align__(8) float2 scoef2[12];   // packed (x,y) per k — for phase A
    __shared__ float scoefS[2][12];   // scalar mirror — for Gram
    __shared__ float beqs[2][4];
    __shared__ float sobs[2][NOBS];
    __shared__ float stgt[6];

    const int tid = threadIdx.x;
    const int b = blockIdx.x;

    // ---- stage LDS
    for (int idx = tid; idx < NVARS * BSTRIDE; idx += 128) {
        int j = idx / BSTRIDE, r = idx % BSTRIDE;
        float v = 0.f;
        if (r < 300) {
            int q = r / 100, t = r % 100;
            const float* Bq = (q == 0) ? P : (q == 1) ? Pd : Pdd;
            v = Bq[t * 11 + j];
        }
        sBc[j][r] = v;
    }
    for (int idx = tid; idx < WS_FLOATS; idx += 128) cst[idx] = ws[idx];
    if (tid < 20) sobs[tid / 10][tid % 10] = obs[b * 20 + tid];
    if (tid == 0) {
        beqs[0][0] = 0.f; beqs[0][1] = ise[b*4+2]; beqs[0][2] = term[b*4+0]; beqs[0][3] = term[b*4+2];
        beqs[1][0] = 0.f; beqs[1][1] = ise[b*4+3]; beqs[1][2] = term[b*4+1]; beqs[1][3] = term[b*4+3];
        stgt[0] = tgt[b*4+0]; stgt[1] = tgt[b*4+2];
        stgt[2] = tgt[b*4+1]; stgt[3] = tgt[b*4+3];
        stgt[4] = dtb[b*2+0]; stgt[5] = dtb[b*2+1];
    }
    __syncthreads();

    // init c_bar (r1-verbatim), lanes tid<22 (wave 0)
    const int ca = tid / 11, cj = tid % 11;   // valid for tid<22
    float lm = 0.f, cb = 0.f;
    if (tid < 22) {
        float bi0 = 0.f, bi1 = beqs[ca][1], bi2 = beqs[ca][2], bi3 = beqs[ca][3];
        float bi4 = via[b*4 + 2*ca + 0], bi5 = via[b*4 + 2*ca + 1];
        const float* E = &cst[E_OFF + cj * 6];
        float s = E[0]*bi0 + E[1]*bi1 + E[2]*bi2 + E[3]*bi3 + E[4]*bi4 + E[5]*bi5;
        cb = s;
        scoefS[ca][cj] = s;
        ((float*)&scoef2[cj])[ca] = s;
    }

    // ---- iteration-invariant caches (A lanes): full basis rows in VGPRs (r4-verbatim)
    float rP[NVARS], rPd[NVARS], rPdd[NVARS];
    {
        const int t = (tid < NUMT) ? tid : 0;
        #pragma unroll
        for (int k = 0; k < NVARS; ++k) {
            rP[k]   = sBc[k][t];
            rPd[k]  = sBc[k][t + 100];
            rPdd[k] = sBc[k][t + 200];
        }
    }
    float obx[NOBS], oby[NOBS];   // wave-uniform -> SGPRs
    #pragma unroll
    for (int o = 0; o < NOBS; ++o) {
        obx[o] = sbcast(sobs[0][o]);
        oby[o] = sbcast(sobs[1][o]);
    }
    // iteration-invariant obstacle-center sum (hoisted out of the per-iter loop)
    float Sobx = 0.f, Soby = 0.f;
    #pragma unroll
    for (int o = 0; o < NOBS; ++o) { Sobx += obx[o]; Soby += oby[o]; }
    const float tg0 = sbcast(stgt[0]), tg1 = sbcast(stgt[1]);
    const float tg2 = sbcast(stgt[2]), tg3 = sbcast(stgt[3]);
    const float tg4 = sbcast(stgt[4]), tg5 = sbcast(stgt[5]);

    float* pwA = &wbc[0][tid];               // + axis*BSTRIDE + q*100
    const int lg = tid - 100;                // Gram lane (0..21), wave-1 idle lanes

    // phase-B task: wave0 lanes 0..32 -> tasks 0..32; wave1 lanes 64..96 -> tasks 33..65
    int btask = -1;
    if (tid <= 32) btask = tid;
    else if (tid >= 64 && tid <= 96) btask = tid - 31;
    const int wi = (btask >= 0) ? btask % 6 : 0;
    const int bjj = (btask >= 0) ? btask / 6 : 0;
    const float4* pbB = (const float4*)(&sBc[0][0] + bjj * BSTRIDE + (wi % 3) * 100);
    const float4* pwB = (const float4*)(&wbc[wi / 3][(wi % 3) * 100]);
    __syncthreads();

    for (int it = 0; it < MAXIT; ++it) {
        // ---- phase A (tid<100): packed-fp32 curve eval + projections
        if (tid < NUMT) {
            f32x2 acc0 = {0.f, 0.f};   // (x, y)
            f32x2 acc1 = {0.f, 0.f};   // (xd, yd)
            f32x2 acc2 = {0.f, 0.f};   // (xdd, ydd)
            #pragma unroll
            for (int k = 0; k < NVARS; ++k) {
                f32x2 c2 = *(const f32x2*)&scoef2[k];
                acc0 += c2 * rP[k];
                acc1 += c2 * rPd[k];
                acc2 += c2 * rPdd[k];
            }
            // obstacles: Sb = sum(d*f); center-sum Sob added once at the end
            f32x2 Sb = {0.f, 0.f};
            #pragma unroll
            for (int o = 0; o < NOBS; ++o) {
                f32x2 ob = {obx[o], oby[o]};
                f32x2 d = acc0 - ob;
                float r2 = fmaf(d.x, d.x, d.y * d.y);
                float f  = fmaxf(1.0f, 0.4f * rsqrtf(fmaxf(r2, 1e-30f)));
                Sb += d * f;
            }
            f32x2 Sob = {Sobx, Soby};
            // velocity: f = max(0.1*rinv, min(1, 2*rinv))
            float r2v = fmaf(acc1.x, acc1.x, acc1.y * acc1.y);
            float riv = rsqrtf(fmaxf(r2v, 1e-24f));
            float fv  = fmaxf(0.1f * riv, fminf(1.0f, 2.0f * riv));
            f32x2 wv  = acc1 * fv;
            // acceleration: f = min(1, 2*rinv)
            float r2a = fmaf(acc2.x, acc2.x, acc2.y * acc2.y);
            float ria = rsqrtf(fmaxf(r2a, 1e-24f));
            float fa  = fminf(1.0f, 2.0f * ria);
            f32x2 wa  = acc2 * fa;
            // target: f = max(dmin*rinv, min(1, dmax*rinv))
            float tt = (float)tid * (5.0f / 99.0f);
            f32x2 tg = {tg0 + tg1 * tt, tg2 + tg3 * tt};
            f32x2 wt = acc0 - tg;
            float r2t = fmaf(wt.x, wt.x, wt.y * wt.y);
            float rit = rsqrtf(fmaxf(r2t, 1e-24f));
            float ftg = fmaxf(tg4 * rit, fminf(1.0f, tg5 * rit));
            f32x2 w0 = ((Sb + Sob) + tg) + wt * ftg;

            pwA[0]   = w0.x;
            pwA[100] = wv.x;
            pwA[200] = wa.x;
            pwA[BSTRIDE]       = w0.y;
            pwA[BSTRIDE + 100] = wv.y;
            pwA[BSTRIDE + 200] = wa.y;
        }
        // ---- Gram matvecs on w1 idle lanes (tid 100..121), || A (bit-exact)
        if (lg >= 0 && lg < 22) {
            const int ga = lg / 11, gj = lg % 11;
            float d4=0.f, d5=0.f, d6=0.f;
            #pragma unroll
            for (int k = 0; k < 11; ++k) {
                float ck = scoefS[ga][k];
                d4 += ck * cst[GP_OFF   + k*11 + gj];
                d5 += ck * cst[GPD_OFF  + k*11 + gj];
                d6 += ck * cst[GPDD_OFF + k*11 + gj];
            }
            sd456[0][lg] = d4; sd456[1][lg] = d5; sd456[2][lg] = d6;
        }
        __syncthreads();

        // ---- phase B (33 tasks per wave): packed f32x2 dots (even/odd chains)
        if (btask >= 0) {
            f32x2 s2 = {0.f, 0.f};
            #pragma unroll
            for (int i = 0; i < 25; ++i) {
                float4 a = pbB[i], w = pwB[i];
                f32x2 alo = {a.x, a.y}, ahi = {a.z, a.w};
                f32x2 wlo = {w.x, w.y}, whi = {w.z, w.w};
                s2 += wlo * alo;
                s2 += whi * ahi;
            }
            Dred[wi][bjj] = s2.x + s2.y;
        }
        __syncthreads();

        // ---- phase C (tid<22, wave 0): combine (r12-verbatim)
        if (tid < 22) {
            float d4 = sd456[0][tid], d5 = sd456[1][tid], d6 = sd456[2][tid];
            int i0 = 3*ca;
            float D0 = Dred[i0][cj], D1 = Dred[i0+1][cj], D2 = Dred[i0+2][cj];
            lm -= (11.f*d4 - D0) + (d5 - D1) + (d6 - D2);
            mlin[ca][cj] = lm + D0 + D1 + D2 + cb;
        }
        // no barrier: C->D producers/consumers are lanes tid<22 of wave 0

        // ---- phase D (tid<22): write both scoef copies
        if (tid < 22) {
            float s = 0.f;
            #pragma unroll
            for (int k = 0; k < 11; ++k) s += cst[F_OFF + cj*11 + k] * mlin[ca][k];
            #pragma unroll
            for (int k = 0; k < 4; ++k)  s += cst[G4_OFF + cj*4 + k] * beqs[ca][k];
            scoefS[ca][cj] = s;
            ((float*)&scoef2[cj])[ca] = s;
        }
        __syncthreads();
    }

    if (tid < 22) out[b * 22 + tid] = scoefS[ca][cj];
}

extern "C" void kernel_launch(void* const* d_in, const int* in_sizes, int n_in,
                              void* d_out, int out_size, void* d_ws, size_t ws_size,
                              hipStream_t stream)
{
    const float* P    = (const float*)d_in[0];
    const float* Pd   = (const float*)d_in[1];
    const float* Pdd  = (const float*)d_in[2];
    const float* ise  = (const float*)d_in[3];
    const float* term = (const float*)d_in[4];
    const float* via  = (const float*)d_in[5];
    const float* obs  = (const float*)d_in[6];
    const float* tgt  = (const float*)d_in[7];
    const float* dtb  = (const float*)d_in[8];
    float* ws  = (float*)d_ws;
    float* out = (float*)d_out;

    const int B = in_sizes[3] / 4;   // 2048

    hipLaunchKernelGGL(setup_kernel, dim3(1), dim3(128), 0, stream, P, Pd, Pdd, ws);
    hipLaunchKernelGGL(solve_kernel, dim3(B), dim3(128), 0, stream,
                       P, Pd, Pdd, ise, term, via, obs, tgt, dtb, ws, out);
}

// Round 18
// 212.268 us; speedup vs baseline: 1.0460x; 1.0460x over previous
//
#include <hip/hip_runtime.h>
#include <math.h>

#define NVARS 11
#define NUMT  100
#define NOBS  10
#define MAXIT 50

// workspace layout (floats) — identical to r1..r17
#define E_OFF    0      // inv_init[:11,11:17]  11x6
#define F_OFF    66     // inv_opt[:11,:11]     11x11
#define G4_OFF   187    // inv_opt[:11,11:15]   11x4
#define GP_OFF   231    // P^T P                11x11
#define GPD_OFF  352    // Pd^T Pd
#define GPDD_OFF 473    // Pdd^T Pdd
#define WS_FLOATS 594

#define BSTRIDE 308     // row stride (16B aligned)

typedef float f32x2 __attribute__((ext_vector_type(2)));

// setup: both KKT inversions run CONCURRENTLY (A17 on lanes 0..50, A15 on 64..108,
// shared barriers). Per-matrix fp64 op sequence is bit-identical to the serial version
// (r17 verified: constants correct; failure there was a solve-side reorder).
__global__ __launch_bounds__(128) void setup_kernel(const float* __restrict__ P,
                                                    const float* __restrict__ Pd,
                                                    const float* __restrict__ Pdd,
                                                    float* __restrict__ ws)
{
    __shared__ double G[3][NVARS][NVARS];
    __shared__ double A17[17][34];
    __shared__ double A15[15][30];
    __shared__ double fac17[17], fac15[15];
    __shared__ int piv17, piv15;
    const int tid = threadIdx.x;

    // Gram matrices in fp64
    for (int idx = tid; idx < 3 * 121; idx += 128) {
        int q = idx / 121, rem = idx % 121, r = rem / 11, c = rem % 11;
        const float* B = (q == 0) ? P : (q == 1) ? Pd : Pdd;
        double s = 0.0;
        for (int t = 0; t < NUMT; ++t) s += (double)B[t * 11 + r] * (double)B[t * 11 + c];
        G[q][r][c] = s;
    }
    __syncthreads();
    for (int idx = tid; idx < 3 * 121; idx += 128) ws[GP_OFF + idx] = (float)((&G[0][0][0])[idx]);

    // ---- build both augmented systems
    for (int idx = tid; idx < 17 * 34; idx += 128) A17[idx / 34][idx % 34] = 0.0;
    for (int idx = tid; idx < 15 * 30; idx += 128) A15[idx / 30][idx % 30] = 0.0;
    __syncthreads();
    for (int idx = tid; idx < 121; idx += 128) {
        int r = idx / 11, c = idx % 11;
        A17[r][c] = G[2][r][c];
        A15[r][c] = 11.0 * G[0][r][c] + G[1][r][c] + G[2][r][c] + ((r == c) ? 1.0 : 0.0);
    }
    if (tid < 66) {   // A17 constraint rows: P0, Pd0, P99, Pd99, P49, P74
        int r = tid / 11, j = tid % 11;
        const float* src = (r == 0) ? P : (r == 1) ? Pd : (r == 2) ? (P + 99 * 11) : (r == 3) ? (Pd + 99 * 11)
                           : (r == 4) ? (P + 49 * 11) : (P + 74 * 11);
        double v = (double)src[j];
        A17[j][11 + r] = v;
        A17[11 + r][j] = v;
    }
    if (tid >= 68 && tid < 112) {   // A15 constraint rows: P0, Pd0, P99, Pd99
        int q = tid - 68;
        int r = q / 11, j = q % 11;
        const float* src = (r == 0) ? P : (r == 1) ? Pd : (r == 2) ? (P + 99 * 11) : (Pd + 99 * 11);
        double v = (double)src[j];
        A15[j][11 + r] = v;
        A15[11 + r][j] = v;
    }
    if (tid < 17) A17[tid][17 + tid] = 1.0;
    if (tid >= 32 && tid < 47) { int r = tid - 32; A15[r][15 + r] = 1.0; }
    __syncthreads();

    // ---- fused Gauss-Jordan: k=0..16 for A17; k<15 steps also advance A15
    for (int k = 0; k < 17; ++k) {
        if (tid == 0) {
            int p = k; double best = fabs(A17[k][k]);
            for (int r = k + 1; r < 17; ++r) { double v = fabs(A17[r][k]); if (v > best) { best = v; p = r; } }
            piv17 = p;
        }
        if (tid == 1 && k < 15) {
            int p = k; double best = fabs(A15[k][k]);
            for (int r = k + 1; r < 15; ++r) { double v = fabs(A15[r][k]); if (v > best) { best = v; p = r; } }
            piv15 = p;
        }
        __syncthreads();
        int p7 = piv17;
        if (p7 != k && tid < 34) { double t = A17[k][tid]; A17[k][tid] = A17[p7][tid]; A17[p7][tid] = t; }
        if (k < 15) {
            int p5 = piv15;
            if (p5 != k && tid >= 64 && tid < 94) {
                int c = tid - 64;
                double t = A15[k][c]; A15[k][c] = A15[p5][c]; A15[p5][c] = t;
            }
        }
        __syncthreads();
        double pv7 = A17[k][k];
        double pv5 = (k < 15) ? A15[k][k] : 1.0;
        __syncthreads();
        if (tid < 34) A17[k][tid] /= pv7;
        else if (tid < 51) fac17[tid - 34] = A17[tid - 34][k];   // fac[k] unused
        if (k < 15) {
            if (tid >= 64 && tid < 94) A15[k][tid - 64] /= pv5;
            else if (tid >= 94 && tid < 109) fac15[tid - 94] = A15[tid - 94][k];
        }
        __syncthreads();
        for (int idx = tid; idx < 17 * 34; idx += 128) {
            int r = idx / 34, c = idx % 34;
            if (r != k) A17[r][c] -= fac17[r] * A17[k][c];
        }
        if (k < 15) {
            for (int idx = tid; idx < 15 * 30; idx += 128) {
                int r = idx / 30, c = idx % 30;
                if (r != k) A15[r][c] -= fac15[r] * A15[k][c];
            }
        }
        __syncthreads();
    }

    if (tid < 66)  { int j = tid / 6,  k = tid % 6;  ws[E_OFF + tid]  = (float)A17[j][17 + 11 + k]; }
    if (tid < 121) { int j = tid / 11, k = tid % 11; ws[F_OFF + tid]  = (float)A15[j][15 + k]; }
    if (tid < 44)  { int j = tid / 4,  k = tid % 4;  ws[G4_OFF + tid] = (float)A15[j][15 + 11 + k]; }
}

__device__ __forceinline__ float sbcast(float v) {
    return __int_as_float(__builtin_amdgcn_readfirstlane(__float_as_int(v)));
}

// solve: r15 VERBATIM (best passing: 184 us dispatch, absmax 0.0625).
// 1 element per 128-thread block (2 waves), grid 2048 = 8 blocks/CU (all resident).
// A on tid<100 (packed f32x2); Gram on w1 lanes 100..121 (|| A); B 33/33 exact-order
// scalar float4 dots (summation order FROZEN — r16/r17 reorders regressed/failed);
// C/D on tid<22.
__global__ __launch_bounds__(128, 4) void solve_kernel(
    const float* __restrict__ P, const float* __restrict__ Pd, const float* __restrict__ Pdd,
    const float* __restrict__ ise, const float* __restrict__ term, const float* __restrict__ via,
    const float* __restrict__ obs, const float* __restrict__ tgt, const float* __restrict__ dtb,
    const float* __restrict__ ws, float* __restrict__ out)
{
    __shared__ __align__(16) float sBc[NVARS][BSTRIDE];   // [j][q*100+t]
    __shared__ __align__(16) float wbc[2][BSTRIDE];       // [axis][q*100+t]
    __shared__ float cst[WS_FLOATS];
    __shared__ float sd456[3][24];    // Gram matvec results (w1 lanes 100..121)
    __shared__ float Dred[6][12];
    __shared__ float mlin[2][12];
    __shared__ __align__(8) float2 scoef2[12];   // packed (x,y) per k — for phase A
    __shared__ float scoefS[2][12];   // scalar mirror — for Gram
    __shared__ float beqs[2][4];
    __shared__ float sobs[2][NOBS];
    __shared__ float stgt[6];

    const int tid = threadIdx.x;
    const int b = blockIdx.x;

    // ---- stage LDS
    for (int idx = tid; idx < NVARS * BSTRIDE; idx += 128) {
        int j = idx / BSTRIDE, r = idx % BSTRIDE;
        float v = 0.f;
        if (r < 300) {
            int q = r / 100, t = r % 100;
            const float* Bq = (q == 0) ? P : (q == 1) ? Pd : Pdd;
            v = Bq[t * 11 + j];
        }
        sBc[j][r] = v;
    }
    for (int idx = tid; idx < WS_FLOATS; idx += 128) cst[idx] = ws[idx];
    if (tid < 20) sobs[tid / 10][tid % 10] = obs[b * 20 + tid];
    if (tid == 0) {
        beqs[0][0] = 0.f; beqs[0][1] = ise[b*4+2]; beqs[0][2] = term[b*4+0]; beqs[0][3] = term[b*4+2];
        beqs[1][0] = 0.f; beqs[1][1] = ise[b*4+3]; beqs[1][2] = term[b*4+1]; beqs[1][3] = term[b*4+3];
        stgt[0] = tgt[b*4+0]; stgt[1] = tgt[b*4+2];
        stgt[2] = tgt[b*4+1]; stgt[3] = tgt[b*4+3];
        stgt[4] = dtb[b*2+0]; stgt[5] = dtb[b*2+1];
    }
    __syncthreads();

    // init c_bar (r1-verbatim), lanes tid<22 (wave 0)
    const int ca = tid / 11, cj = tid % 11;   // valid for tid<22
    float lm = 0.f, cb = 0.f;
    if (tid < 22) {
        float bi0 = 0.f, bi1 = beqs[ca][1], bi2 = beqs[ca][2], bi3 = beqs[ca][3];
        float bi4 = via[b*4 + 2*ca + 0], bi5 = via[b*4 + 2*ca + 1];
        const float* E = &cst[E_OFF + cj * 6];
        float s = E[0]*bi0 + E[1]*bi1 + E[2]*bi2 + E[3]*bi3 + E[4]*bi4 + E[5]*bi5;
        cb = s;
        scoefS[ca][cj] = s;
        ((float*)&scoef2[cj])[ca] = s;
    }

    // ---- iteration-invariant caches (A lanes): full basis rows in VGPRs
    float rP[NVARS], rPd[NVARS], rPdd[NVARS];
    {
        const int t = (tid < NUMT) ? tid : 0;
        #pragma unroll
        for (int k = 0; k < NVARS; ++k) {
            rP[k]   = sBc[k][t];
            rPd[k]  = sBc[k][t + 100];
            rPdd[k] = sBc[k][t + 200];
        }
    }
    float obx[NOBS], oby[NOBS];   // wave-uniform -> SGPRs
    #pragma unroll
    for (int o = 0; o < NOBS; ++o) {
        obx[o] = sbcast(sobs[0][o]);
        oby[o] = sbcast(sobs[1][o]);
    }
    const float tg0 = sbcast(stgt[0]), tg1 = sbcast(stgt[1]);
    const float tg2 = sbcast(stgt[2]), tg3 = sbcast(stgt[3]);
    const float tg4 = sbcast(stgt[4]), tg5 = sbcast(stgt[5]);

    float* pwA = &wbc[0][tid];               // + axis*BSTRIDE + q*100
    const int lg = tid - 100;                // Gram lane (0..21), wave-1 idle lanes

    // phase-B task: wave0 lanes 0..32 -> tasks 0..32; wave1 lanes 64..96 -> tasks 33..65
    int btask = -1;
    if (tid <= 32) btask = tid;
    else if (tid >= 64 && tid <= 96) btask = tid - 31;
    const int wi = (btask >= 0) ? btask % 6 : 0;
    const int bjj = (btask >= 0) ? btask / 6 : 0;
    const float4* pbB = (const float4*)(&sBc[0][0] + bjj * BSTRIDE + (wi % 3) * 100);
    const float4* pwB = (const float4*)(&wbc[wi / 3][(wi % 3) * 100]);
    __syncthreads();

    for (int it = 0; it < MAXIT; ++it) {
        // ---- phase A (tid<100): packed-fp32 curve eval + projections (r15-verbatim)
        if (tid < NUMT) {
            f32x2 acc0 = {0.f, 0.f};   // (x, y)
            f32x2 acc1 = {0.f, 0.f};   // (xd, yd)
            f32x2 acc2 = {0.f, 0.f};   // (xdd, ydd)
            #pragma unroll
            for (int k = 0; k < NVARS; ++k) {
                f32x2 c2 = *(const f32x2*)&scoef2[k];
                acc0 += c2 * rP[k];
                acc1 += c2 * rPd[k];
                acc2 += c2 * rPdd[k];
            }
            // obstacles (div-free, packed push; per-o ob add — r15 order)
            f32x2 Sb = {0.f, 0.f};
            #pragma unroll
            for (int o = 0; o < NOBS; ++o) {
                f32x2 ob = {obx[o], oby[o]};
                f32x2 d = acc0 - ob;
                float r2 = fmaf(d.x, d.x, d.y * d.y);
                float f  = fmaxf(1.0f, 0.4f * rsqrtf(fmaxf(r2, 1e-30f)));
                Sb += d * f + ob;
            }
            // velocity: f = max(0.1*rinv, min(1, 2*rinv))
            float r2v = fmaf(acc1.x, acc1.x, acc1.y * acc1.y);
            float riv = rsqrtf(fmaxf(r2v, 1e-24f));
            float fv  = fmaxf(0.1f * riv, fminf(1.0f, 2.0f * riv));
            f32x2 wv  = acc1 * fv;
            // acceleration: f = min(1, 2*rinv)
            float r2a = fmaf(acc2.x, acc2.x, acc2.y * acc2.y);
            float ria = rsqrtf(fmaxf(r2a, 1e-24f));
            float fa  = fminf(1.0f, 2.0f * ria);
            f32x2 wa  = acc2 * fa;
            // target: f = max(dmin*rinv, min(1, dmax*rinv))
            float tt = (float)tid * (5.0f / 99.0f);
            f32x2 tg = {tg0 + tg1 * tt, tg2 + tg3 * tt};
            f32x2 wt = acc0 - tg;
            float r2t = fmaf(wt.x, wt.x, wt.y * wt.y);
            float rit = rsqrtf(fmaxf(r2t, 1e-24f));
            float ftg = fmaxf(tg4 * rit, fminf(1.0f, tg5 * rit));
            f32x2 w0 = (Sb + tg) + wt * ftg;

            pwA[0]   = w0.x;
            pwA[100] = wv.x;
            pwA[200] = wa.x;
            pwA[BSTRIDE]       = w0.y;
            pwA[BSTRIDE + 100] = wv.y;
            pwA[BSTRIDE + 200] = wa.y;
        }
        // ---- Gram matvecs on w1 idle lanes (tid 100..121), || A (bit-exact)
        if (lg >= 0 && lg < 22) {
            const int ga = lg / 11, gj = lg % 11;
            float d4=0.f, d5=0.f, d6=0.f;
            #pragma unroll
            for (int k = 0; k < 11; ++k) {
                float ck = scoefS[ga][k];
                d4 += ck * cst[GP_OFF   + k*11 + gj];
                d5 += ck * cst[GPD_OFF  + k*11 + gj];
                d6 += ck * cst[GPDD_OFF + k*11 + gj];
            }
            sd456[0][lg] = d4; sd456[1][lg] = d5; sd456[2][lg] = d6;
        }
        __syncthreads();

        // ---- phase B (33 tasks per wave): scalar float4 dots, exact t-order (FROZEN)
        if (btask >= 0) {
            float s = 0.f;
            #pragma unroll
            for (int i = 0; i < 25; ++i) {
                float4 a = pbB[i], w = pwB[i];
                s += w.x * a.x; s += w.y * a.y; s += w.z * a.z; s += w.w * a.w;
            }
            Dred[wi][bjj] = s;
        }
        __syncthreads();

        // ---- phase C (tid<22, wave 0): combine (r12-verbatim)
        if (tid < 22) {
            float d4 = sd456[0][tid], d5 = sd456[1][tid], d6 = sd456[2][tid];
            int i0 = 3*ca;
            float D0 = Dred[i0][cj], D1 = Dred[i0+1][cj], D2 = Dred[i0+2][cj];
            lm -= (11.f*d4 - D0) + (d5 - D1) + (d6 - D2);
            mlin[ca][cj] = lm + D0 + D1 + D2 + cb;
        }
        // no barrier: C->D producers/consumers are lanes tid<22 of wave 0

        // ---- phase D (tid<22): write both scoef copies
        if (tid < 22) {
            float s = 0.f;
            #pragma unroll
            for (int k = 0; k < 11; ++k) s += cst[F_OFF + cj*11 + k] * mlin[ca][k];
            #pragma unroll
            for (int k = 0; k < 4; ++k)  s += cst[G4_OFF + cj*4 + k] * beqs[ca][k];
            scoefS[ca][cj] = s;
            ((float*)&scoef2[cj])[ca] = s;
        }
        __syncthreads();
    }

    if (tid < 22) out[b * 22 + tid] = scoefS[ca][cj];
}

extern "C" void kernel_launch(void* const* d_in, const int* in_sizes, int n_in,
                              void* d_out, int out_size, void* d_ws, size_t ws_size,
                              hipStream_t stream)
{
    const float* P    = (const float*)d_in[0];
    const float* Pd   = (const float*)d_in[1];
    const float* Pdd  = (const float*)d_in[2];
    const float* ise  = (const float*)d_in[3];
    const float* term = (const float*)d_in[4];
    const float* via  = (const float*)d_in[5];
    const float* obs  = (const float*)d_in[6];
    const float* tgt  = (const float*)d_in[7];
    const float* dtb  = (const float*)d_in[8];
    float* ws  = (float*)d_ws;
    float* out = (float*)d_out;

    const int B = in_sizes[3] / 4;   // 2048

    hipLaunchKernelGGL(setup_kernel, dim3(1), dim3(128), 0, stream, P, Pd, Pdd, ws);
    hipLaunchKernelGGL(solve_kernel, dim3(B), dim3(128), 0, stream,
                       P, Pd, Pdd, ise, term, via, obs, tgt, dtb, ws, out);
}